// Round 2
// baseline (697.433 us; speedup 1.0000x reference)
//
#include <hip/hip_runtime.h>
#include <hip/hip_bf16.h>
#include <hip/hip_fp16.h>

typedef _Float16 half8 __attribute__((ext_vector_type(8)));
typedef float f32x4 __attribute__((ext_vector_type(4)));

#define IN_DIM 784
#define KPAD   832            // 13 * 64
#define NKT    13
#define HIDDEN 8192
#define BATCH  16384
#define OUTD   10
#define N1 (HIDDEN * IN_DIM)  // 6422528
#define J1 (N1 / 2)
#define N2 (OUTD * HIDDEN)    // 81920
#define J2 (N2 / 2)

// ---- workspace layout (bytes) ----
#define WS_META   0                               // u32[4]: T1,cut1,T2,cut2
#define WS_SEL1   64                              // u32[4]: c_lt, j_rem, prefix, spare
#define WS_SEL2   96
#define WS_EQ1    128                             // u32[256]: cnt + up to 255 idx
#define WS_EQ2    1152
#define WS_HA1    4096
#define WS_HB1    (WS_HA1 + 8192)
#define WS_HC1    (WS_HB1 + 8192)
#define WS_HA2    (WS_HC1 + 8192)
#define WS_HB2    (WS_HA2 + 8192)
#define WS_HC2    (WS_HB2 + 8192)
#define CTL_BYTES 65536
#define WS_LOG    65536                           // [16384][10] f32 = 655,360 (atomic acc)
#define WS_XH     (WS_LOG + BATCH * OUTD * 4)     // [16384][832] f16 = 27,262,976
#define WS_W1H    (WS_XH + (size_t)BATCH * KPAD * 2)   // [8192][832] f16 = 13,631,488
#define WS_W2H    (WS_W1H + (size_t)HIDDEN * KPAD * 2) // [16][8192] f16 = 262,144
#define WS_NEED   (WS_W2H + 16 * HIDDEN * 2)      // ~41.9 MB total

#define ZERO_WORDS ((CTL_BYTES + BATCH * OUTD * 4) / 4)   // ctl + logits
#define SEL1J (WS_SEL1 / 4 + 1)
#define SEL2J (WS_SEL2 / 4 + 1)

// ---------------- zero ctl + logits (j_rem seeds written inline) ----------------
__global__ void zero_ws(unsigned* ws) {
  for (int i = blockIdx.x * 256 + threadIdx.x; i < ZERO_WORDS; i += gridDim.x * 256) {
    unsigned v = 0u;
    if (i == SEL1J) v = J1;
    else if (i == SEL2J) v = J2;
    ws[i] = v;
  }
}

// ---------------- radix-select histograms ----------------
// pass 0: bin = key>>21 ; pass 1: prefix(11b) match, bin = (key>>10)&0x7FF ;
// pass 2: prefix(21b) match, bin = key & 0x3FF
__global__ void hist_pass(const float* __restrict__ s, int n,
                          unsigned* __restrict__ hist,
                          const unsigned* __restrict__ sel, int pass) {
  __shared__ unsigned lh[2048];
  for (int i = threadIdx.x; i < 2048; i += 256) lh[i] = 0u;
  __syncthreads();
  unsigned prefix = sel[2];
  for (int i = blockIdx.x * 256 + threadIdx.x; i < n; i += gridDim.x * 256) {
    unsigned k = __float_as_uint(s[i]) & 0x7FFFFFFFu;
    int bin = -1;
    if (pass == 0)                       bin = (int)(k >> 21);
    else if (pass == 1) { if ((k >> 21) == prefix) bin = (int)((k >> 10) & 0x7FFu); }
    else                { if ((k >> 10) == prefix) bin = (int)(k & 0x3FFu); }
    if (bin >= 0) atomicAdd(&lh[bin], 1u);
  }
  __syncthreads();
  for (int i = threadIdx.x; i < 2048; i += 256)
    if (lh[i]) atomicAdd(&hist[i], lh[i]);
}

__global__ void scan_pass(const unsigned* __restrict__ hist, int nbins,
                          unsigned* __restrict__ sel, int bits) {
  __shared__ unsigned part[256];
  int per = nbins / 256;
  unsigned ssum = 0;
  for (int i = 0; i < per; ++i) ssum += hist[threadIdx.x * per + i];
  part[threadIdx.x] = ssum;
  __syncthreads();
  if (threadIdx.x == 0) {
    unsigned jrem = sel[1];
    unsigned cum = 0;
    int seg = 0;
    for (; seg < 255; ++seg) { if (cum + part[seg] > jrem) break; cum += part[seg]; }
    int b = seg * per;
    for (;; ++b) { unsigned h = hist[b]; if (cum + h > jrem) break; cum += h; }
    sel[0] += cum;                       // c_lt accumulates
    sel[1] = jrem - cum;                 // local rank within bin
    sel[2] = (sel[2] << bits) | (unsigned)b;
  }
}

__global__ void collect_eq(const float* __restrict__ s, int n,
                           const unsigned* __restrict__ sel, unsigned* __restrict__ eq) {
  unsigned T = sel[2];
  for (int i = blockIdx.x * 256 + threadIdx.x; i < n; i += gridDim.x * 256) {
    unsigned k = __float_as_uint(s[i]) & 0x7FFFFFFFu;
    if (k == T) {
      unsigned p = atomicAdd(&eq[0], 1u);
      if (p < 255u) eq[1 + p] = (unsigned)i;
    }
  }
}

// replicate stable-argsort tie semantics: exclude the m = j - c_lt smallest-index ties
__global__ void finalize_sel(const unsigned* __restrict__ sel, unsigned* __restrict__ eq,
                             unsigned* __restrict__ meta, int slot) {
  unsigned m = sel[1];
  unsigned ce = eq[0]; if (ce > 255u) ce = 255u;
  unsigned cut;
  if (m == 0u) cut = 0u;
  else if (m >= ce) cut = 0xFFFFFFFFu;
  else {
    for (unsigned a = 0; a <= m; ++a) {        // partial selection sort
      unsigned best = a;
      for (unsigned b = a + 1; b < ce; ++b) if (eq[1 + b] < eq[1 + best]) best = b;
      unsigned t = eq[1 + a]; eq[1 + a] = eq[1 + best]; eq[1 + best] = t;
    }
    cut = eq[1 + m];   // kept iff flat index >= cut
  }
  meta[slot * 2]     = sel[2];
  meta[slot * 2 + 1] = cut;
}

// ---------------- converts (f32 -> padded f16) ----------------
__global__ void cvt_x(const float* __restrict__ x, _Float16* __restrict__ xh) {
  int c = blockIdx.x * 256 + threadIdx.x;       // 16384*104 chunks of 8
  int row = c / 104, cc = c % 104;
  half8 v;
#pragma unroll
  for (int j = 0; j < 8; ++j) {
    int col = cc * 8 + j;
    float f = (col < IN_DIM) ? x[(size_t)row * IN_DIM + col] : 0.f;
    v[j] = (_Float16)f;
  }
  *(half8*)(xh + (size_t)row * KPAD + cc * 8) = v;
}

__global__ void cvt_w1(const float* __restrict__ w, const float* __restrict__ sc,
                       const unsigned* __restrict__ meta, _Float16* __restrict__ wh) {
  int c = blockIdx.x * 256 + threadIdx.x;       // 8192*104
  int row = c / 104, cc = c % 104;
  unsigned T = meta[0], cut = meta[1];
  half8 v;
#pragma unroll
  for (int j = 0; j < 8; ++j) {
    int col = cc * 8 + j;
    float f = 0.f;
    if (col < IN_DIM) {
      unsigned flat = (unsigned)(row * IN_DIM + col);
      unsigned k = __float_as_uint(sc[flat]) & 0x7FFFFFFFu;
      bool keep = (k > T) || (k == T && flat >= cut);
      f = keep ? w[flat] : 0.f;
    }
    v[j] = (_Float16)f;
  }
  *(half8*)(wh + (size_t)row * KPAD + cc * 8) = v;
}

__global__ void cvt_w2(const float* __restrict__ w, const float* __restrict__ sc,
                       const unsigned* __restrict__ meta, _Float16* __restrict__ wh) {
  int c = blockIdx.x * 256 + threadIdx.x;       // 16*1024
  int o = c >> 10, cc = c & 1023;
  unsigned T = meta[2], cut = meta[3];
  half8 v;
#pragma unroll
  for (int j = 0; j < 8; ++j) {
    float f = 0.f;
    if (o < OUTD) {
      unsigned flat = (unsigned)(o * HIDDEN + cc * 8 + j);
      unsigned k = __float_as_uint(sc[flat]) & 0x7FFFFFFFu;
      bool keep = (k > T) || (k == T && flat >= cut);
      f = keep ? w[flat] : 0.f;
    }
    v[j] = (_Float16)f;
  }
  *(half8*)(wh + (size_t)o * HIDDEN + cc * 8) = v;
}

// ---------------- fused GEMM1 + relu + GEMM2-partial ----------------
__device__ __forceinline__ void gload16(const _Float16* g, _Float16* l) {
  __builtin_amdgcn_global_load_lds((const __attribute__((address_space(1))) void*)g,
                                   (__attribute__((address_space(3))) void*)l, 16, 0, 0);
}

__global__ __launch_bounds__(256) void gemm_fused(
    const _Float16* __restrict__ xh, const _Float16* __restrict__ w1h,
    const _Float16* __restrict__ w2h, float* __restrict__ logits) {
  __shared__ __align__(16) char smem[45056];     // 16K sA | 16K sB ; reused: 36K hbuf + 8K plog
  _Float16* sA = (_Float16*)smem;
  _Float16* sB = (_Float16*)(smem + 16384);

  const int tid  = threadIdx.x;
  const int lane = tid & 63;
  const int wid  = tid >> 6;
  const int wm   = wid >> 1, wn = wid & 1;

  // XCD swizzle (8192 % 8 == 0 -> bijective) + GROUP_M=8 for L2
  int swz = (blockIdx.x & 7) * 1024 + (blockIdx.x >> 3);
  int grp = swz >> 9;            // /512
  int rem = swz & 511;
  int pm  = grp * 8 + (rem & 7); // 0..127
  int pn  = rem >> 3;            // 0..63

  const _Float16* xbase = xh  + (size_t)pm * 128 * KPAD;
  const _Float16* bbase = w1h + (size_t)pn * 128 * KPAD;

  f32x4 acc[4][4] = {};

  for (int kt = 0; kt < NKT; ++kt) {
    // stage 16KB A + 16KB B, 16B/lane, source pre-swizzled (chunk ^ row&7)
#pragma unroll
    for (int cc = 0; cc < 4; ++cc) {
      int slot = cc * 256 + tid;
      int row = slot >> 3, chs = slot & 7;
      int cl = chs ^ (row & 7);
      gload16(xbase + (size_t)row * KPAD + kt * 64 + cl * 8, sA + slot * 8);
      gload16(bbase + (size_t)row * KPAD + kt * 64 + cl * 8, sB + slot * 8);
    }
    __syncthreads();
#pragma unroll
    for (int ks = 0; ks < 2; ++ks) {
      half8 af[4], bf[4];
#pragma unroll
      for (int mi = 0; mi < 4; ++mi) {
        int row = wm * 64 + mi * 16 + (lane & 15);
        int chs = (ks * 4 + (lane >> 4)) ^ (row & 7);
        af[mi] = *(const half8*)(sA + row * 64 + chs * 8);
      }
#pragma unroll
      for (int ni = 0; ni < 4; ++ni) {
        int row = wn * 64 + ni * 16 + (lane & 15);
        int chs = (ks * 4 + (lane >> 4)) ^ (row & 7);
        bf[ni] = *(const half8*)(sB + row * 64 + chs * 8);
      }
#pragma unroll
      for (int mi = 0; mi < 4; ++mi)
#pragma unroll
        for (int ni = 0; ni < 4; ++ni)
          acc[mi][ni] = __builtin_amdgcn_mfma_f32_16x16x32_f16(af[mi], bf[ni], acc[mi][ni], 0, 0, 0);
    }
    __syncthreads();
  }

  // ---- epilogue: logits partial = relu(h) @ w2m^T over this block's 128 n-cols ----
  _Float16* hb  = (_Float16*)smem + wid * (64 * 72);   // per-wave [64][72] f16
  float* plog   = (float*)(smem + 36864);              // [128][16] f32

  for (int i = tid; i < 2048; i += 256) plog[i] = 0.f; // zero (before barrier)

#pragma unroll
  for (int mi = 0; mi < 4; ++mi) {
    int r0 = mi * 16 + (lane >> 4) * 4;
#pragma unroll
    for (int ni = 0; ni < 4; ++ni) {
      int cl = ni * 16 + (lane & 15);
#pragma unroll
      for (int j = 0; j < 4; ++j) {
        float v = acc[mi][ni][j];
        hb[(r0 + j) * 72 + cl] = (_Float16)(v > 0.f ? v : 0.f);
      }
    }
  }
  __syncthreads();   // plog zero + hb visible

  half8 wb[2];
#pragma unroll
  for (int ks = 0; ks < 2; ++ks) {
    int o = lane & 15;
    int kg = pn * 128 + wn * 64 + ks * 32 + (lane >> 4) * 8;
    wb[ks] = *(const half8*)(w2h + (size_t)o * HIDDEN + kg);
  }
  f32x4 lacc[4] = {};
#pragma unroll
  for (int mi = 0; mi < 4; ++mi) {
#pragma unroll
    for (int ks = 0; ks < 2; ++ks) {
      int row = mi * 16 + (lane & 15);
      half8 a = *(const half8*)(hb + row * 72 + ks * 32 + (lane >> 4) * 8);
      lacc[mi] = __builtin_amdgcn_mfma_f32_16x16x32_f16(a, wb[ks], lacc[mi], 0, 0, 0);
    }
  }
  {
    int o = lane & 15;
    if (o < OUTD) {
#pragma unroll
      for (int mi = 0; mi < 4; ++mi)
#pragma unroll
        for (int j = 0; j < 4; ++j) {
          int row = wm * 64 + mi * 16 + (lane >> 4) * 4 + j;
          atomicAdd(&plog[row * 16 + o], lacc[mi][j]);
        }
    }
  }
  __syncthreads();
  // one global atomic per (row, o): 64 n-blocks accumulate into logits
  for (int i = tid; i < 128 * OUTD; i += 256) {
    int row = i / OUTD, oo = i % OUTD;
    atomicAdd(&logits[((size_t)pm * 128 + row) * OUTD + oo], plog[row * 16 + oo]);
  }
}

// ---------------- log_softmax ----------------
__global__ void final_ls(const float* __restrict__ logits, float* __restrict__ out) {
  int row = blockIdx.x * 256 + threadIdx.x;     // 16384
  float l[OUTD];
#pragma unroll
  for (int o = 0; o < OUTD; ++o) l[o] = logits[(size_t)row * OUTD + o];
  float mx = l[0];
#pragma unroll
  for (int o = 1; o < OUTD; ++o) mx = fmaxf(mx, l[o]);
  float s = 0.f;
#pragma unroll
  for (int o = 0; o < OUTD; ++o) s += expf(l[o] - mx);
  float lse = mx + logf(s);
#pragma unroll
  for (int o = 0; o < OUTD; ++o) out[(size_t)row * OUTD + o] = l[o] - lse;
}

// ---------------- launch ----------------
extern "C" void kernel_launch(void* const* d_in, const int* in_sizes, int n_in,
                              void* d_out, int out_size, void* d_ws, size_t ws_size,
                              hipStream_t stream) {
  if (ws_size < (size_t)WS_NEED) return;        // fail validation cleanly, never corrupt

  const float* x  = (const float*)d_in[0];
  const float* w1 = (const float*)d_in[1];
  const float* s1 = (const float*)d_in[2];
  const float* w2 = (const float*)d_in[3];
  const float* s2 = (const float*)d_in[4];

  char* ws = (char*)d_ws;
  unsigned* meta = (unsigned*)(ws + WS_META);
  unsigned* sel1 = (unsigned*)(ws + WS_SEL1);
  unsigned* sel2 = (unsigned*)(ws + WS_SEL2);
  unsigned* eq1  = (unsigned*)(ws + WS_EQ1);
  unsigned* eq2  = (unsigned*)(ws + WS_EQ2);
  unsigned* hA1  = (unsigned*)(ws + WS_HA1);
  unsigned* hB1  = (unsigned*)(ws + WS_HB1);
  unsigned* hC1  = (unsigned*)(ws + WS_HC1);
  unsigned* hA2  = (unsigned*)(ws + WS_HA2);
  unsigned* hB2  = (unsigned*)(ws + WS_HB2);
  unsigned* hC2  = (unsigned*)(ws + WS_HC2);
  float*    logits = (float*)(ws + WS_LOG);
  _Float16* xh   = (_Float16*)(ws + WS_XH);
  _Float16* w1h  = (_Float16*)(ws + WS_W1H);
  _Float16* w2h  = (_Float16*)(ws + WS_W2H);
  float* out = (float*)d_out;

  zero_ws<<<704, 256, 0, stream>>>((unsigned*)ws);
  cvt_x<<<(BATCH * 104) / 256, 256, 0, stream>>>(x, xh);  // independent of selection

  hist_pass<<<1024, 256, 0, stream>>>(s1, N1, hA1, sel1, 0);
  hist_pass<<<64,   256, 0, stream>>>(s2, N2, hA2, sel2, 0);
  scan_pass<<<1, 256, 0, stream>>>(hA1, 2048, sel1, 11);
  scan_pass<<<1, 256, 0, stream>>>(hA2, 2048, sel2, 11);
  hist_pass<<<1024, 256, 0, stream>>>(s1, N1, hB1, sel1, 1);
  hist_pass<<<64,   256, 0, stream>>>(s2, N2, hB2, sel2, 1);
  scan_pass<<<1, 256, 0, stream>>>(hB1, 2048, sel1, 11);
  scan_pass<<<1, 256, 0, stream>>>(hB2, 2048, sel2, 11);
  hist_pass<<<1024, 256, 0, stream>>>(s1, N1, hC1, sel1, 2);
  hist_pass<<<64,   256, 0, stream>>>(s2, N2, hC2, sel2, 2);
  scan_pass<<<1, 256, 0, stream>>>(hC1, 1024, sel1, 10);
  scan_pass<<<1, 256, 0, stream>>>(hC2, 1024, sel2, 10);
  collect_eq<<<1024, 256, 0, stream>>>(s1, N1, sel1, eq1);
  collect_eq<<<64,   256, 0, stream>>>(s2, N2, sel2, eq2);
  finalize_sel<<<1, 1, 0, stream>>>(sel1, eq1, meta, 0);
  finalize_sel<<<1, 1, 0, stream>>>(sel2, eq2, meta, 1);

  cvt_w1<<<(HIDDEN * 104) / 256, 256, 0, stream>>>(w1, s1, meta, w1h);
  cvt_w2<<<(16 * 1024) / 256,    256, 0, stream>>>(w2, s2, meta, w2h);

  gemm_fused<<<128 * 64, 256, 0, stream>>>(xh, w1h, w2h, logits);
  final_ls<<<BATCH / 256, 256, 0, stream>>>(logits, out);
}

// Round 3
// 583.778 us; speedup vs baseline: 1.1947x; 1.1947x over previous
//
#include <hip/hip_runtime.h>
#include <hip/hip_fp16.h>

typedef _Float16 half8 __attribute__((ext_vector_type(8)));
typedef float f32x4 __attribute__((ext_vector_type(4)));
typedef unsigned long long u64;
typedef unsigned u32;

#define IN_DIM 784
#define KPAD   832            // 13 * 64
#define NKT    13
#define HIDDEN 8192
#define BATCH  16384
#define OUTD   10
#define N1 (HIDDEN * IN_DIM)  // 6422528
#define J1 (N1 / 2)
#define N2 (OUTD * HIDDEN)    // 81920
#define J2 (N2 / 2)

// ---- workspace layout (bytes) ----
#define WS_META  0        // u32[4]: T1,cut1,T2,cut2
#define WS_SEL1  64       // u32[2]: {jrem, prefix}
#define WS_SEL2  96
#define WS_CNT   128      // u32[2]: candidate counts
#define WS_H01   4096     // 2048 u32 (s1 pass0)
#define WS_H02   12288    // 2048 u32 (s2 pass0)
#define WS_H11   20480    // 1024 u32 (s1 pass1)
#define WS_H12   24576    // 1024 u32 (s2 pass1)
#define CTL_ZERO 28672    // zero range [0, CTL_ZERO)
#define WS_CAND1 32768    // 8192 u64
#define WS_CAND2 98304    // 8192 u64
#define WS_LOG   163840   // [16384][10] f32 atomic accumulator
#define WS_XH    (WS_LOG + BATCH * OUTD * 4)           // [16384][832] f16
#define WS_W1H   (WS_XH + (size_t)BATCH * KPAD * 2)    // [8192][832] f16
#define WS_W2H   (WS_W1H + (size_t)HIDDEN * KPAD * 2)  // [16][8192] f16
#define WS_NEED  (WS_W2H + 16 * HIDDEN * 2)

#define CTL_WORDS (CTL_ZERO / 4)                       // 7168
#define ZERO_WORDS (CTL_WORDS + BATCH * OUTD)          // + logits

// ---------------- zero ctl/hists + logits, seed jrem ----------------
__global__ void zero_ws(u32* ws) {
  for (int i = blockIdx.x * 256 + threadIdx.x; i < ZERO_WORDS; i += gridDim.x * 256) {
    if (i < CTL_WORDS) {
      u32 v = 0u;
      if (i == WS_SEL1 / 4) v = J1;
      else if (i == WS_SEL2 / 4) v = J2;
      ws[i] = v;
    } else {
      ws[WS_LOG / 4 + (i - CTL_WORDS)] = 0u;
    }
  }
}

// ---------------- radix-select: 2 histogram passes + candidate collect ----------------
// key = |score| bit pattern (31 bits, monotonic). pass0: bins on key>>20 (11b).
// pass1: among (key>>20)==prefix11, bins on (key>>10)&0x3FF. collect: (key>>10)==prefix21.
__global__ void sel_hist(const float* __restrict__ s1, const float* __restrict__ s2,
                         u32* __restrict__ ws, int pass) {
  __shared__ u32 lh[2048];
  const int nbins = pass == 0 ? 2048 : 1024;
  for (int i = threadIdx.x; i < nbins; i += 256) lh[i] = 0u;
  __syncthreads();
  const float* s; int n, bid, nb; u32* hist; const u32* sel;
  if (blockIdx.x < 1024) {
    s = s1; n = N1; bid = blockIdx.x; nb = 1024;
    hist = ws + (pass == 0 ? WS_H01 : WS_H11) / 4; sel = ws + WS_SEL1 / 4;
  } else {
    s = s2; n = N2; bid = blockIdx.x - 1024; nb = 64;
    hist = ws + (pass == 0 ? WS_H02 : WS_H12) / 4; sel = ws + WS_SEL2 / 4;
  }
  u32 prefix = sel[1];
  for (int i = bid * 256 + threadIdx.x; i < n; i += nb * 256) {
    u32 k = __float_as_uint(s[i]) & 0x7FFFFFFFu;
    if (pass == 0) atomicAdd(&lh[k >> 20], 1u);
    else if ((k >> 20) == prefix) atomicAdd(&lh[(k >> 10) & 0x3FFu], 1u);
  }
  __syncthreads();
  for (int i = threadIdx.x; i < nbins; i += 256)
    if (lh[i]) atomicAdd(&hist[i], lh[i]);
}

__global__ void sel_scan(u32* __restrict__ ws, int pass) {
  __shared__ u32 part[256];
  const int nbins = pass == 0 ? 2048 : 1024;
  const int bits  = pass == 0 ? 11 : 10;
  u32* hist = ws + ((blockIdx.x == 0) ? (pass == 0 ? WS_H01 : WS_H11)
                                      : (pass == 0 ? WS_H02 : WS_H12)) / 4;
  u32* sel  = ws + ((blockIdx.x == 0) ? WS_SEL1 : WS_SEL2) / 4;
  int per = nbins / 256;
  u32 ssum = 0;
  for (int i = 0; i < per; ++i) ssum += hist[threadIdx.x * per + i];
  part[threadIdx.x] = ssum;
  __syncthreads();
  if (threadIdx.x == 0) {
    u32 jrem = sel[0];
    u32 cum = 0; int seg = 0;
    for (; seg < 255; ++seg) { if (cum + part[seg] > jrem) break; cum += part[seg]; }
    int b = seg * per;
    for (;; ++b) { u32 h = hist[b]; if (cum + h > jrem) break; cum += h; }
    sel[0] = jrem - cum;
    sel[1] = (sel[1] << bits) | (u32)b;
  }
}

__global__ void sel_collect(const float* __restrict__ s1, const float* __restrict__ s2,
                            u32* __restrict__ ws) {
  const float* s; int n, bid, nb; u64* cand; u32* cnt; const u32* sel;
  if (blockIdx.x < 1024) {
    s = s1; n = N1; bid = blockIdx.x; nb = 1024;
    cand = (u64*)(ws + WS_CAND1 / 4); cnt = ws + WS_CNT / 4; sel = ws + WS_SEL1 / 4;
  } else {
    s = s2; n = N2; bid = blockIdx.x - 1024; nb = 64;
    cand = (u64*)(ws + WS_CAND2 / 4); cnt = ws + WS_CNT / 4 + 1; sel = ws + WS_SEL2 / 4;
  }
  u32 prefix21 = sel[1];
  for (int i = bid * 256 + threadIdx.x; i < n; i += nb * 256) {
    u32 k = __float_as_uint(s[i]) & 0x7FFFFFFFu;
    if ((k >> 10) == prefix21) {
      u32 p = atomicAdd(cnt, 1u);
      if (p < 8192u) cand[p] = ((u64)k << 32) | (u32)i;
    }
  }
}

// exact rank-m candidate by (key, idx) -> stable argsort tie semantics
__global__ void sel_final(u32* __restrict__ ws) {
  int t = blockIdx.x;
  const u64* cand = (const u64*)(ws + (t == 0 ? WS_CAND1 : WS_CAND2) / 4);
  u32 n = ws[WS_CNT / 4 + t]; if (n > 8192u) n = 8192u;
  u32 m = ws[(t == 0 ? WS_SEL1 : WS_SEL2) / 4];   // jrem after both scans
  for (u32 ci = threadIdx.x; ci < n; ci += 256) {
    u64 me = cand[ci];
    u32 r = 0;
    for (u32 j = 0; j < n; ++j) r += (cand[j] < me) ? 1u : 0u;
    if (r == m) {
      ws[WS_META / 4 + t * 2]     = (u32)(me >> 32);   // T
      ws[WS_META / 4 + t * 2 + 1] = (u32)me;           // cut (flat idx)
    }
  }
}

// ---------------- converts (f32 -> padded f16) ----------------
__global__ void cvt_x(const float* __restrict__ x, _Float16* __restrict__ xh) {
  int c = blockIdx.x * 256 + threadIdx.x;       // 16384*104 chunks of 8
  int row = c / 104, cc = c % 104;
  half8 v;
#pragma unroll
  for (int j = 0; j < 8; ++j) {
    int col = cc * 8 + j;
    float f = (col < IN_DIM) ? x[(size_t)row * IN_DIM + col] : 0.f;
    v[j] = (_Float16)f;
  }
  *(half8*)(xh + (size_t)row * KPAD + cc * 8) = v;
}

__global__ void cvt_w12(const float* __restrict__ w1, const float* __restrict__ s1,
                        const float* __restrict__ w2, const float* __restrict__ s2,
                        const u32* __restrict__ meta,
                        _Float16* __restrict__ w1h, _Float16* __restrict__ w2h) {
  if (blockIdx.x < 3328) {
    int c = blockIdx.x * 256 + threadIdx.x;     // 8192*104
    int row = c / 104, cc = c % 104;
    u32 T = meta[0], cut = meta[1];
    half8 v;
#pragma unroll
    for (int j = 0; j < 8; ++j) {
      int col = cc * 8 + j;
      float f = 0.f;
      if (col < IN_DIM) {
        u32 flat = (u32)(row * IN_DIM + col);
        u32 k = __float_as_uint(s1[flat]) & 0x7FFFFFFFu;
        bool keep = (k > T) || (k == T && flat >= cut);
        f = keep ? w1[flat] : 0.f;
      }
      v[j] = (_Float16)f;
    }
    *(half8*)(w1h + (size_t)row * KPAD + cc * 8) = v;
  } else {
    int c = (blockIdx.x - 3328) * 256 + threadIdx.x;   // 16*1024
    int o = c >> 10, cc = c & 1023;
    u32 T = meta[2], cut = meta[3];
    half8 v;
#pragma unroll
    for (int j = 0; j < 8; ++j) {
      float f = 0.f;
      if (o < OUTD) {
        u32 flat = (u32)(o * HIDDEN + cc * 8 + j);
        u32 k = __float_as_uint(s2[flat]) & 0x7FFFFFFFu;
        bool keep = (k > T) || (k == T && flat >= cut);
        f = keep ? w2[flat] : 0.f;
      }
      v[j] = (_Float16)f;
    }
    *(half8*)(w2h + (size_t)o * HIDDEN + cc * 8) = v;
  }
}

// ---------------- fused GEMM1 + relu + GEMM2 epilogue (256x256, dbuf BK=64) ----------------
__device__ __forceinline__ void gload16(const _Float16* g, _Float16* l) {
  __builtin_amdgcn_global_load_lds((const __attribute__((address_space(1))) void*)g,
                                   (__attribute__((address_space(3))) void*)l, 16, 0, 0);
}

__global__ __launch_bounds__(512, 2) void gemm_fused(
    const _Float16* __restrict__ xh, const _Float16* __restrict__ w1h,
    const _Float16* __restrict__ w2h, float* __restrict__ logits) {
  extern __shared__ __align__(16) char smem[];   // 131072: 2 x (32K A | 32K B)

  const int tid  = threadIdx.x;
  const int lane = tid & 63;
  const int wid  = tid >> 6;          // 8 waves: 2M x 4N
  const int wm   = wid >> 2, wn = wid & 3;

  // XCD-bijective swizzle (2048 % 8 == 0) + pm-group-of-8: per-XCD K-slice fits L2
  int v   = (blockIdx.x & 7) * 256 + (blockIdx.x >> 3);
  int g   = v >> 8, r = v & 255;
  int pm  = g * 8 + (r & 7);          // 0..63
  int pn  = r >> 3;                   // 0..31

  const _Float16* Ab = xh  + (size_t)pm * 256 * KPAD;
  const _Float16* Bb = w1h + (size_t)pn * 256 * KPAD;

  f32x4 acc[8][4] = {};

  auto stage = [&](int kt, int b) {
    _Float16* dA = (_Float16*)(smem + b * 65536);
    _Float16* dB = (_Float16*)(smem + b * 65536 + 32768);
#pragma unroll
    for (int i = 0; i < 4; ++i) {
      int slot = i * 512 + tid;                 // 0..2047
      int row  = slot >> 3, ch = slot & 7;
      int cl   = ch ^ (row & 7);                // pre-swizzled source, linear LDS dest
      gload16(Ab + (size_t)row * KPAD + kt * 64 + cl * 8, dA + slot * 8);
      gload16(Bb + (size_t)row * KPAD + kt * 64 + cl * 8, dB + slot * 8);
    }
  };

  stage(0, 0);
  for (int t = 0; t < NKT; ++t) {
    __syncthreads();                  // drains stage(t) (issued a full tile ago) + barrier
    if (t + 1 < NKT) stage(t + 1, (t + 1) & 1);   // in flight across this tile's compute
    const _Float16* sA = (const _Float16*)(smem + (t & 1) * 65536);
    const _Float16* sB = sA + 16384;
#pragma unroll
    for (int ks = 0; ks < 2; ++ks) {
      half8 af[8], bf[4];
#pragma unroll
      for (int mi = 0; mi < 8; ++mi) {
        int row = wm * 128 + mi * 16 + (lane & 15);
        int ch  = (ks * 4 + (lane >> 4)) ^ (row & 7);
        af[mi] = *(const half8*)(sA + row * 64 + ch * 8);
      }
#pragma unroll
      for (int ni = 0; ni < 4; ++ni) {
        int row = wn * 64 + ni * 16 + (lane & 15);
        int ch  = (ks * 4 + (lane >> 4)) ^ (row & 7);
        bf[ni] = *(const half8*)(sB + row * 64 + ch * 8);
      }
      __builtin_amdgcn_s_setprio(1);
#pragma unroll
      for (int mi = 0; mi < 8; ++mi)
#pragma unroll
        for (int ni = 0; ni < 4; ++ni)
          acc[mi][ni] = __builtin_amdgcn_mfma_f32_16x16x32_f16(af[mi], bf[ni], acc[mi][ni], 0, 0, 0);
      __builtin_amdgcn_s_setprio(0);
    }
  }

  // ---- epilogue: logits += relu(h) @ w2m^T over this block's 256 n-cols ----
  __syncthreads();                               // all staged-LDS reads done; reuse LDS
  _Float16* hb = (_Float16*)smem + wid * (64 * 72);   // per-wave [64][72] f16 (73.7 KB)
  float* plog  = (float*)(smem + 73728);              // [256][16] f32 (16 KB)

  for (int i = tid; i < 256 * 16; i += 512) plog[i] = 0.f;

  // round 0: rows mi 0..3
#pragma unroll
  for (int mi = 0; mi < 4; ++mi) {
    int r0 = mi * 16 + (lane >> 4) * 4;
#pragma unroll
    for (int ni = 0; ni < 4; ++ni) {
      int cl = ni * 16 + (lane & 15);
#pragma unroll
      for (int j = 0; j < 4; ++j) {
        float q = acc[mi][ni][j];
        hb[(r0 + j) * 72 + cl] = (_Float16)(q > 0.f ? q : 0.f);
      }
    }
  }
  __syncthreads();                               // plog zero visible (hb is wave-private)

  half8 wb[2];
  int o = lane & 15;
#pragma unroll
  for (int ks = 0; ks < 2; ++ks)
    wb[ks] = *(const half8*)(w2h + (size_t)o * HIDDEN + pn * 256 + wn * 64 + ks * 32 + (lane >> 4) * 8);

  f32x4 lacc[8] = {};
#pragma unroll
  for (int mi = 0; mi < 4; ++mi)
#pragma unroll
    for (int ks = 0; ks < 2; ++ks) {
      int row = mi * 16 + (lane & 15);
      half8 a = *(const half8*)(hb + row * 72 + ks * 32 + (lane >> 4) * 8);
      lacc[mi] = __builtin_amdgcn_mfma_f32_16x16x32_f16(a, wb[ks], lacc[mi], 0, 0, 0);
    }

  // round 1: rows mi 4..7 (wave-private WAR on hb; compiler orders via lgkmcnt)
#pragma unroll
  for (int mi = 4; mi < 8; ++mi) {
    int r0 = (mi - 4) * 16 + (lane >> 4) * 4;
#pragma unroll
    for (int ni = 0; ni < 4; ++ni) {
      int cl = ni * 16 + (lane & 15);
#pragma unroll
      for (int j = 0; j < 4; ++j) {
        float q = acc[mi][ni][j];
        hb[(r0 + j) * 72 + cl] = (_Float16)(q > 0.f ? q : 0.f);
      }
    }
  }
#pragma unroll
  for (int mi = 4; mi < 8; ++mi)
#pragma unroll
    for (int ks = 0; ks < 2; ++ks) {
      int row = (mi - 4) * 16 + (lane & 15);
      half8 a = *(const half8*)(hb + row * 72 + ks * 32 + (lane >> 4) * 8);
      lacc[mi] = __builtin_amdgcn_mfma_f32_16x16x32_f16(a, wb[ks], lacc[mi], 0, 0, 0);
    }

  if (o < OUTD) {
#pragma unroll
    for (int mi = 0; mi < 8; ++mi)
#pragma unroll
      for (int j = 0; j < 4; ++j) {
        int row = wm * 128 + mi * 16 + (lane >> 4) * 4 + j;
        atomicAdd(&plog[row * 16 + o], lacc[mi][j]);
      }
  }
  __syncthreads();
  for (int i = tid; i < 256 * OUTD; i += 512) {
    int row = i / OUTD, oo = i % OUTD;
    atomicAdd(&logits[((size_t)pm * 256 + row) * OUTD + oo], plog[row * 16 + oo]);
  }
}

// ---------------- log_softmax ----------------
__global__ void final_ls(const float* __restrict__ logits, float* __restrict__ out) {
  int row = blockIdx.x * 256 + threadIdx.x;     // 16384
  float l[OUTD];
#pragma unroll
  for (int oo = 0; oo < OUTD; ++oo) l[oo] = logits[(size_t)row * OUTD + oo];
  float mx = l[0];
#pragma unroll
  for (int oo = 1; oo < OUTD; ++oo) mx = fmaxf(mx, l[oo]);
  float s = 0.f;
#pragma unroll
  for (int oo = 0; oo < OUTD; ++oo) s += expf(l[oo] - mx);
  float lse = mx + logf(s);
#pragma unroll
  for (int oo = 0; oo < OUTD; ++oo) out[(size_t)row * OUTD + oo] = l[oo] - lse;
}

// ---------------- launch ----------------
extern "C" void kernel_launch(void* const* d_in, const int* in_sizes, int n_in,
                              void* d_out, int out_size, void* d_ws, size_t ws_size,
                              hipStream_t stream) {
  if (ws_size < (size_t)WS_NEED) return;

  const float* x  = (const float*)d_in[0];
  const float* w1 = (const float*)d_in[1];
  const float* s1 = (const float*)d_in[2];
  const float* w2 = (const float*)d_in[3];
  const float* s2 = (const float*)d_in[4];

  char* ws = (char*)d_ws;
  u32*  wsu = (u32*)ws;
  float* logits = (float*)(ws + WS_LOG);
  _Float16* xh  = (_Float16*)(ws + WS_XH);
  _Float16* w1h = (_Float16*)(ws + WS_W1H);
  _Float16* w2h = (_Float16*)(ws + WS_W2H);
  float* out = (float*)d_out;

  (void)hipFuncSetAttribute((const void*)gemm_fused,
                            hipFuncAttributeMaxDynamicSharedMemorySize, 131072);

  zero_ws<<<668, 256, 0, stream>>>(wsu);
  cvt_x<<<(BATCH * 104) / 256, 256, 0, stream>>>(x, xh);

  sel_hist<<<1088, 256, 0, stream>>>(s1, s2, wsu, 0);
  sel_scan<<<2, 256, 0, stream>>>(wsu, 0);
  sel_hist<<<1088, 256, 0, stream>>>(s1, s2, wsu, 1);
  sel_scan<<<2, 256, 0, stream>>>(wsu, 1);
  sel_collect<<<1088, 256, 0, stream>>>(s1, s2, wsu);
  sel_final<<<2, 256, 0, stream>>>(wsu);

  cvt_w12<<<3392, 256, 0, stream>>>(w1, s1, w2, s2, wsu + WS_META / 4, w1h, w2h);

  gemm_fused<<<2048, 512, 131072, stream>>>(xh, w1h, w2h, logits);
  final_ls<<<BATCH / 256, 256, 0, stream>>>(logits, out);
}

// Round 4
// 564.856 us; speedup vs baseline: 1.2347x; 1.0335x over previous
//
#include <hip/hip_runtime.h>
#include <hip/hip_fp16.h>

typedef _Float16 half8 __attribute__((ext_vector_type(8)));
typedef float f32x4 __attribute__((ext_vector_type(4)));
typedef unsigned long long u64;
typedef unsigned u32;

#define IN_DIM 784
#define KPAD   832            // 13 * 64
#define NKT    13
#define HIDDEN 8192
#define BATCH  16384
#define OUTD   10
#define N1 (HIDDEN * IN_DIM)  // 6422528
#define J1 (N1 / 2)
#define N2 (OUTD * HIDDEN)    // 81920
#define J2 (N2 / 2)

// ---- workspace layout (bytes) ----
#define WS_META  0        // u32[4]: T1,cut1,T2,cut2
#define WS_SEL1  64       // u32[2]: {jrem, prefix}
#define WS_SEL2  96
#define WS_CNT   128      // u32[2]: candidate counts
#define WS_H01   4096     // 2048 u32 (s1 pass0)
#define WS_H02   12288    // 2048 u32 (s2 pass0)
#define WS_H11   20480    // 1024 u32 (s1 pass1)
#define WS_H12   24576    // 1024 u32 (s2 pass1)
#define CTL_ZERO 28672    // zero range [0, CTL_ZERO)
#define WS_CAND1 32768    // 8192 u64
#define WS_CAND2 98304    // 8192 u64
#define WS_LOG   163840   // [16384][10] f32 atomic accumulator
#define WS_XH    (WS_LOG + BATCH * OUTD * 4)           // [16384][832] f16
#define WS_W1H   (WS_XH + (size_t)BATCH * KPAD * 2)    // [8192][832] f16
#define WS_W2H   (WS_W1H + (size_t)HIDDEN * KPAD * 2)  // [16][8192] f16
#define WS_NEED  (WS_W2H + 16 * HIDDEN * 2)

#define CTL_WORDS (CTL_ZERO / 4)                       // 7168
#define ZERO_WORDS (CTL_WORDS + BATCH * OUTD)          // + logits
#define CVT_X_BLKS 6656
#define ZERO_BLKS  668

// ---------------- cvt_x fused with ws zeroing ----------------
__global__ void cvt_x_zero(const float* __restrict__ x, _Float16* __restrict__ xh,
                           u32* __restrict__ ws) {
  if (blockIdx.x < CVT_X_BLKS) {
    int c = blockIdx.x * 256 + threadIdx.x;     // 16384*104 chunks of 8
    int row = c / 104, cc = c % 104;
    half8 v;
#pragma unroll
    for (int j = 0; j < 8; ++j) {
      int col = cc * 8 + j;
      float f = (col < IN_DIM) ? x[(size_t)row * IN_DIM + col] : 0.f;
      v[j] = (_Float16)f;
    }
    *(half8*)(xh + (size_t)row * KPAD + cc * 8) = v;
  } else {
    int bb = blockIdx.x - CVT_X_BLKS;
    for (int i = bb * 256 + threadIdx.x; i < ZERO_WORDS; i += ZERO_BLKS * 256) {
      if (i < CTL_WORDS) {
        u32 v = 0u;
        if (i == WS_SEL1 / 4) v = J1;
        else if (i == WS_SEL2 / 4) v = J2;
        ws[i] = v;
      } else {
        ws[WS_LOG / 4 + (i - CTL_WORDS)] = 0u;
      }
    }
  }
}

// ---------------- radix-select: 2 histogram passes + candidate collect ----------------
// key = |score| bit pattern (31 bits, monotonic). pass0: bins on key>>20 (11b).
// pass1: among (key>>20)==prefix11, bins on (key>>10)&0x3FF. collect: (key>>10)==prefix21.
__global__ void sel_hist(const float* __restrict__ s1, const float* __restrict__ s2,
                         u32* __restrict__ ws, int pass) {
  __shared__ u32 lh[2048];
  const int nbins = pass == 0 ? 2048 : 1024;
  for (int i = threadIdx.x; i < nbins; i += 256) lh[i] = 0u;
  __syncthreads();
  const float* s; int n, bid, nb; u32* hist; const u32* sel;
  if (blockIdx.x < 1024) {
    s = s1; n = N1; bid = blockIdx.x; nb = 1024;
    hist = ws + (pass == 0 ? WS_H01 : WS_H11) / 4; sel = ws + WS_SEL1 / 4;
  } else {
    s = s2; n = N2; bid = blockIdx.x - 1024; nb = 64;
    hist = ws + (pass == 0 ? WS_H02 : WS_H12) / 4; sel = ws + WS_SEL2 / 4;
  }
  u32 prefix = sel[1];
  for (int i = bid * 256 + threadIdx.x; i < n; i += nb * 256) {
    u32 k = __float_as_uint(s[i]) & 0x7FFFFFFFu;
    if (pass == 0) atomicAdd(&lh[k >> 20], 1u);
    else if ((k >> 20) == prefix) atomicAdd(&lh[(k >> 10) & 0x3FFu], 1u);
  }
  __syncthreads();
  for (int i = threadIdx.x; i < nbins; i += 256)
    if (lh[i]) atomicAdd(&hist[i], lh[i]);
}

// parallel scan (Hillis-Steele over 256 segment sums), then <=8-bin serial tail
__global__ void sel_scan(u32* __restrict__ ws, int pass) {
  __shared__ u32 part[256], incl[256];
  const int nbins = pass == 0 ? 2048 : 1024;
  const int bits  = pass == 0 ? 11 : 10;
  u32* hist = ws + ((blockIdx.x == 0) ? (pass == 0 ? WS_H01 : WS_H11)
                                      : (pass == 0 ? WS_H02 : WS_H12)) / 4;
  u32* sel  = ws + ((blockIdx.x == 0) ? WS_SEL1 : WS_SEL2) / 4;
  const int per = nbins / 256;
  const int base = threadIdx.x * per;
  u32 ssum = 0;
  for (int i = 0; i < per; ++i) ssum += hist[base + i];
  part[threadIdx.x] = ssum;
  incl[threadIdx.x] = ssum;
  __syncthreads();
  for (int off = 1; off < 256; off <<= 1) {
    u32 v = (threadIdx.x >= off) ? incl[threadIdx.x - off] : 0u;
    __syncthreads();
    incl[threadIdx.x] += v;
    __syncthreads();
  }
  u32 jrem = sel[0];
  u32 excl = incl[threadIdx.x] - part[threadIdx.x];
  if (jrem >= excl && jrem < excl + part[threadIdx.x]) {   // unique owner thread
    u32 cum = excl; int b = base;
    for (;; ++b) { u32 h = hist[b]; if (cum + h > jrem) break; cum += h; }
    sel[0] = jrem - cum;
    sel[1] = (sel[1] << bits) | (u32)b;
  }
}

__global__ void sel_collect(const float* __restrict__ s1, const float* __restrict__ s2,
                            u32* __restrict__ ws) {
  const float* s; int n, bid, nb; u64* cand; u32* cnt; const u32* sel;
  if (blockIdx.x < 1024) {
    s = s1; n = N1; bid = blockIdx.x; nb = 1024;
    cand = (u64*)(ws + WS_CAND1 / 4); cnt = ws + WS_CNT / 4; sel = ws + WS_SEL1 / 4;
  } else {
    s = s2; n = N2; bid = blockIdx.x - 1024; nb = 64;
    cand = (u64*)(ws + WS_CAND2 / 4); cnt = ws + WS_CNT / 4 + 1; sel = ws + WS_SEL2 / 4;
  }
  u32 prefix21 = sel[1];
  for (int i = bid * 256 + threadIdx.x; i < n; i += nb * 256) {
    u32 k = __float_as_uint(s[i]) & 0x7FFFFFFFu;
    if ((k >> 10) == prefix21) {
      u32 p = atomicAdd(cnt, 1u);
      if (p < 8192u) cand[p] = ((u64)k << 32) | (u32)i;
    }
  }
}

// exact rank-m candidate by (key, idx) -> stable argsort tie semantics (LDS-staged)
__global__ void sel_final(u32* __restrict__ ws) {
  __shared__ u64 lc[4096];
  int t = blockIdx.x;
  const u64* cand = (const u64*)(ws + (t == 0 ? WS_CAND1 : WS_CAND2) / 4);
  u32 n = ws[WS_CNT / 4 + t]; if (n > 8192u) n = 8192u;
  u32 nl = n < 4096u ? n : 4096u;
  for (u32 i = threadIdx.x; i < nl; i += 256) lc[i] = cand[i];
  __syncthreads();
  u32 m = ws[(t == 0 ? WS_SEL1 : WS_SEL2) / 4];   // jrem after both scans
  for (u32 ci = threadIdx.x; ci < n; ci += 256) {
    u64 me = (ci < nl) ? lc[ci] : cand[ci];
    u32 r = 0;
    for (u32 j = 0; j < nl; ++j) r += (lc[j] < me) ? 1u : 0u;
    for (u32 j = nl; j < n; ++j) r += (cand[j] < me) ? 1u : 0u;
    if (r == m) {
      ws[WS_META / 4 + t * 2]     = (u32)(me >> 32);   // T
      ws[WS_META / 4 + t * 2 + 1] = (u32)me;           // cut (flat idx)
    }
  }
}

// ---------------- masked weight converts (f32 -> padded f16) ----------------
__global__ void cvt_w12(const float* __restrict__ w1, const float* __restrict__ s1,
                        const float* __restrict__ w2, const float* __restrict__ s2,
                        const u32* __restrict__ meta,
                        _Float16* __restrict__ w1h, _Float16* __restrict__ w2h) {
  if (blockIdx.x < 3328) {
    int c = blockIdx.x * 256 + threadIdx.x;     // 8192*104
    int row = c / 104, cc = c % 104;
    u32 T = meta[0], cut = meta[1];
    half8 v;
#pragma unroll
    for (int j = 0; j < 8; ++j) {
      int col = cc * 8 + j;
      float f = 0.f;
      if (col < IN_DIM) {
        u32 flat = (u32)(row * IN_DIM + col);
        u32 k = __float_as_uint(s1[flat]) & 0x7FFFFFFFu;
        bool keep = (k > T) || (k == T && flat >= cut);
        f = keep ? w1[flat] : 0.f;
      }
      v[j] = (_Float16)f;
    }
    *(half8*)(w1h + (size_t)row * KPAD + cc * 8) = v;
  } else {
    int c = (blockIdx.x - 3328) * 256 + threadIdx.x;   // 16*1024
    int o = c >> 10, cc = c & 1023;
    u32 T = meta[2], cut = meta[3];
    half8 v;
#pragma unroll
    for (int j = 0; j < 8; ++j) {
      float f = 0.f;
      if (o < OUTD) {
        u32 flat = (u32)(o * HIDDEN + cc * 8 + j);
        u32 k = __float_as_uint(s2[flat]) & 0x7FFFFFFFu;
        bool keep = (k > T) || (k == T && flat >= cut);
        f = keep ? w2[flat] : 0.f;
      }
      v[j] = (_Float16)f;
    }
    *(half8*)(w2h + (size_t)o * HIDDEN + cc * 8) = v;
  }
}

// ---------------- fused GEMM1 + relu + GEMM2 epilogue ----------------
// 256x256 tile, BK=64, dbuf, DEPTH-2 prefetch with counted vmcnt (never 0 in loop)
__device__ __forceinline__ void gload16(const _Float16* g, _Float16* l) {
  __builtin_amdgcn_global_load_lds((const __attribute__((address_space(1))) void*)g,
                                   (__attribute__((address_space(3))) void*)l, 16, 0, 0);
}

__global__ __launch_bounds__(512, 2) void gemm_fused(
    const _Float16* __restrict__ xh, const _Float16* __restrict__ w1h,
    const _Float16* __restrict__ w2h, float* __restrict__ logits) {
  extern __shared__ __align__(16) char smem[];   // 131072: 2 x (32K A | 32K B)

  const int tid  = threadIdx.x;
  const int lane = tid & 63;
  const int wid  = tid >> 6;          // 8 waves: 2M x 4N
  const int wm   = wid >> 2, wn = wid & 3;

  // XCD-bijective swizzle (2048 % 8 == 0) + pm-group-of-8: per-XCD K-slice fits L2
  int v   = (blockIdx.x & 7) * 256 + (blockIdx.x >> 3);
  int g   = v >> 8, r = v & 255;
  int pm  = g * 8 + (r & 7);          // 0..63
  int pn  = r >> 3;                   // 0..31

  const _Float16* Ab = xh  + (size_t)pm * 256 * KPAD;
  const _Float16* Bb = w1h + (size_t)pn * 256 * KPAD;

  f32x4 acc[8][4] = {};

  // stage full 64KB tile (A+B) for K-step kt into buffer b: 8 gloads/thread
  auto stage = [&](int kt, int b) {
    _Float16* dA = (_Float16*)(smem + b * 65536);
    _Float16* dB = (_Float16*)(smem + b * 65536 + 32768);
#pragma unroll
    for (int i = 0; i < 4; ++i) {
      int slot = i * 512 + tid;                 // 0..2047
      int row  = slot >> 3, ch = slot & 7;
      int cl   = ch ^ (row & 7);                // pre-swizzled source, linear LDS dest
      gload16(Ab + (size_t)row * KPAD + kt * 64 + cl * 8, dA + slot * 8);
      gload16(Bb + (size_t)row * KPAD + kt * 64 + cl * 8, dB + slot * 8);
    }
  };

  auto compute = [&](int t) {
    const _Float16* sA = (const _Float16*)(smem + (t & 1) * 65536);
    const _Float16* sB = sA + 16384;
#pragma unroll
    for (int ks = 0; ks < 2; ++ks) {
      half8 af[8], bf[4];
#pragma unroll
      for (int mi = 0; mi < 8; ++mi) {
        int row = wm * 128 + mi * 16 + (lane & 15);
        int ch  = (ks * 4 + (lane >> 4)) ^ (row & 7);
        af[mi] = *(const half8*)(sA + row * 64 + ch * 8);
      }
#pragma unroll
      for (int ni = 0; ni < 4; ++ni) {
        int row = wn * 64 + ni * 16 + (lane & 15);
        int ch  = (ks * 4 + (lane >> 4)) ^ (row & 7);
        bf[ni] = *(const half8*)(sB + row * 64 + ch * 8);
      }
      __builtin_amdgcn_s_setprio(1);
#pragma unroll
      for (int mi = 0; mi < 8; ++mi)
#pragma unroll
        for (int ni = 0; ni < 4; ++ni)
          acc[mi][ni] = __builtin_amdgcn_mfma_f32_16x16x32_f16(af[mi], bf[ni], acc[mi][ni], 0, 0, 0);
      __builtin_amdgcn_s_setprio(0);
    }
  };

  // prologue: 2 tiles in flight (16 loads/thread outstanding)
  stage(0, 0);
  stage(1, 1);

  // steady state: vmcnt(8) retires exactly stage(t); stage(t+2) reuses buffer
  // released by compute(t) (after lgkmcnt(0)+barrier). Never drain to 0.
  for (int t = 0; t < NKT - 1; ++t) {
    asm volatile("s_waitcnt vmcnt(8)" ::: "memory");   // stage(t) complete
    __builtin_amdgcn_s_barrier();                      // all waves see buf t
    compute(t);
    asm volatile("s_waitcnt lgkmcnt(0)" ::: "memory"); // my ds_reads of buf t done
    __builtin_amdgcn_s_barrier();                      // all waves released buf t
    if (t + 2 < NKT) stage(t + 2, t & 1);              // overwrite buf t
  }
  // peeled last tile: only stage(12) outstanding
  asm volatile("s_waitcnt vmcnt(0)" ::: "memory");
  __builtin_amdgcn_s_barrier();
  compute(NKT - 1);

  // ---- epilogue: logits += relu(h) @ w2m^T over this block's 256 n-cols ----
  __syncthreads();                               // reads done; reuse LDS
  _Float16* hb = (_Float16*)smem + wid * (64 * 72);   // per-wave [64][72] f16
  float* plog  = (float*)(smem + 73728);              // [256][16] f32

  for (int i = tid; i < 256 * 16; i += 512) plog[i] = 0.f;

  // round 0: rows mi 0..3
#pragma unroll
  for (int mi = 0; mi < 4; ++mi) {
    int r0 = mi * 16 + (lane >> 4) * 4;
#pragma unroll
    for (int ni = 0; ni < 4; ++ni) {
      int cl = ni * 16 + (lane & 15);
#pragma unroll
      for (int j = 0; j < 4; ++j) {
        float q = acc[mi][ni][j];
        hb[(r0 + j) * 72 + cl] = (_Float16)(q > 0.f ? q : 0.f);
      }
    }
  }
  __syncthreads();                               // plog zero visible (hb wave-private)

  half8 wb[2];
  int o = lane & 15;
#pragma unroll
  for (int ks = 0; ks < 2; ++ks)
    wb[ks] = *(const half8*)(w2h + (size_t)o * HIDDEN + pn * 256 + wn * 64 + ks * 32 + (lane >> 4) * 8);

  f32x4 lacc[8] = {};
#pragma unroll
  for (int mi = 0; mi < 4; ++mi)
#pragma unroll
    for (int ks = 0; ks < 2; ++ks) {
      int row = mi * 16 + (lane & 15);
      half8 a = *(const half8*)(hb + row * 72 + ks * 32 + (lane >> 4) * 8);
      lacc[mi] = __builtin_amdgcn_mfma_f32_16x16x32_f16(a, wb[ks], lacc[mi], 0, 0, 0);
    }

  // round 1: rows mi 4..7 (wave-private WAR on hb; compiler orders via lgkmcnt)
#pragma unroll
  for (int mi = 4; mi < 8; ++mi) {
    int r0 = (mi - 4) * 16 + (lane >> 4) * 4;
#pragma unroll
    for (int ni = 0; ni < 4; ++ni) {
      int cl = ni * 16 + (lane & 15);
#pragma unroll
      for (int j = 0; j < 4; ++j) {
        float q = acc[mi][ni][j];
        hb[(r0 + j) * 72 + cl] = (_Float16)(q > 0.f ? q : 0.f);
      }
    }
  }
#pragma unroll
  for (int mi = 4; mi < 8; ++mi)
#pragma unroll
    for (int ks = 0; ks < 2; ++ks) {
      int row = (mi - 4) * 16 + (lane & 15);
      half8 a = *(const half8*)(hb + row * 72 + ks * 32 + (lane >> 4) * 8);
      lacc[mi] = __builtin_amdgcn_mfma_f32_16x16x32_f16(a, wb[ks], lacc[mi], 0, 0, 0);
    }

  if (o < OUTD) {
#pragma unroll
    for (int mi = 0; mi < 8; ++mi)
#pragma unroll
      for (int j = 0; j < 4; ++j) {
        int row = wm * 128 + mi * 16 + (lane >> 4) * 4 + j;
        atomicAdd(&plog[row * 16 + o], lacc[mi][j]);
      }
  }
  __syncthreads();
  for (int i = tid; i < 256 * OUTD; i += 512) {
    int row = i / OUTD, oo = i % OUTD;
    atomicAdd(&logits[((size_t)pm * 256 + row) * OUTD + oo], plog[row * 16 + oo]);
  }
}

// ---------------- log_softmax ----------------
__global__ void final_ls(const float* __restrict__ logits, float* __restrict__ out) {
  int row = blockIdx.x * 256 + threadIdx.x;     // 16384
  float l[OUTD];
#pragma unroll
  for (int oo = 0; oo < OUTD; ++oo) l[oo] = logits[(size_t)row * OUTD + oo];
  float mx = l[0];
#pragma unroll
  for (int oo = 1; oo < OUTD; ++oo) mx = fmaxf(mx, l[oo]);
  float s = 0.f;
#pragma unroll
  for (int oo = 0; oo < OUTD; ++oo) s += expf(l[oo] - mx);
  float lse = mx + logf(s);
#pragma unroll
  for (int oo = 0; oo < OUTD; ++oo) out[(size_t)row * OUTD + oo] = l[oo] - lse;
}

// ---------------- launch ----------------
extern "C" void kernel_launch(void* const* d_in, const int* in_sizes, int n_in,
                              void* d_out, int out_size, void* d_ws, size_t ws_size,
                              hipStream_t stream) {
  if (ws_size < (size_t)WS_NEED) return;

  const float* x  = (const float*)d_in[0];
  const float* w1 = (const float*)d_in[1];
  const float* s1 = (const float*)d_in[2];
  const float* w2 = (const float*)d_in[3];
  const float* s2 = (const float*)d_in[4];

  char* ws = (char*)d_ws;
  u32*  wsu = (u32*)ws;
  float* logits = (float*)(ws + WS_LOG);
  _Float16* xh  = (_Float16*)(ws + WS_XH);
  _Float16* w1h = (_Float16*)(ws + WS_W1H);
  _Float16* w2h = (_Float16*)(ws + WS_W2H);
  float* out = (float*)d_out;

  (void)hipFuncSetAttribute((const void*)gemm_fused,
                            hipFuncAttributeMaxDynamicSharedMemorySize, 131072);

  cvt_x_zero<<<CVT_X_BLKS + ZERO_BLKS, 256, 0, stream>>>(x, xh, wsu);

  sel_hist<<<1088, 256, 0, stream>>>(s1, s2, wsu, 0);
  sel_scan<<<2, 256, 0, stream>>>(wsu, 0);
  sel_hist<<<1088, 256, 0, stream>>>(s1, s2, wsu, 1);
  sel_scan<<<2, 256, 0, stream>>>(wsu, 1);
  sel_collect<<<1088, 256, 0, stream>>>(s1, s2, wsu);
  sel_final<<<2, 256, 0, stream>>>(wsu);

  cvt_w12<<<3392, 256, 0, stream>>>(w1, s1, w2, s2, wsu + WS_META / 4, w1h, w2h);

  gemm_fused<<<2048, 512, 131072, stream>>>(xh, w1h, w2h, logits);
  final_ls<<<BATCH / 256, 256, 0, stream>>>(logits, out);
}